// Round 22
// baseline (359.006 us; speedup 1.0000x reference)
//
#include <hip/hip_runtime.h>
#include <math.h>

#define M0 131072
#define NC 4096
#define FDIM 324   // 6*54
#define APW 4      // atoms per wave (sorted idx -> mostly same crystal)

typedef __attribute__((ext_vector_type(8))) short bf16x8;
typedef __attribute__((ext_vector_type(4))) float f32x4;
typedef __attribute__((ext_vector_type(4))) int   i32x4;

// ---- DS reads, wait INSIDE block. ALL outputs early-clobber ("=&v"): the
// reads land asynchronously, so no output may alias the address input (R20's
// failure mode under high VGPR pressure).
#define DSWIN21(w0, w1, w2, w3, w4, g, addr)                                   \
  asm volatile("ds_read2_b64 %0, %6 offset0:0 offset1:1\n\t"                   \
               "ds_read2_b64 %1, %6 offset0:2 offset1:3\n\t"                   \
               "ds_read2_b64 %2, %6 offset0:4 offset1:5\n\t"                   \
               "ds_read2_b64 %3, %6 offset0:6 offset1:7\n\t"                   \
               "ds_read2_b64 %4, %6 offset0:8 offset1:9\n\t"                   \
               "ds_read_b32 %5, %6 offset:80\n\t"                              \
               "s_waitcnt lgkmcnt(0)"                                          \
               : "=&v"(w0), "=&v"(w1), "=&v"(w2), "=&v"(w3), "=&v"(w4),        \
                 "=&v"(g)                                                      \
               : "v"(addr))

#define DSWIN24(w0, w1, w2, w3, w4, w5, addr)                                  \
  asm volatile("ds_read_b128 %0, %6 offset:0\n\t"                              \
               "ds_read_b128 %1, %6 offset:16\n\t"                             \
               "ds_read_b128 %2, %6 offset:32\n\t"                             \
               "ds_read_b128 %3, %6 offset:48\n\t"                             \
               "ds_read_b128 %4, %6 offset:64\n\t"                             \
               "ds_read_b128 %5, %6 offset:80\n\t"                             \
               "s_waitcnt lgkmcnt(0)"                                          \
               : "=&v"(w0), "=&v"(w1), "=&v"(w2), "=&v"(w3), "=&v"(w4),        \
                 "=&v"(w5)                                                     \
               : "v"(addr))

#define DSWQ5(q, addr)                                                         \
  asm volatile("ds_read_b128 %0, %5 offset:0\n\t"                              \
               "ds_read_b128 %1, %5 offset:16\n\t"                             \
               "ds_read_b128 %2, %5 offset:32\n\t"                             \
               "ds_read_b128 %3, %5 offset:48\n\t"                             \
               "ds_read_b128 %4, %5 offset:64\n\t"                             \
               "s_waitcnt lgkmcnt(0)"                                          \
               : "=&v"(q[0]), "=&v"(q[1]), "=&v"(q[2]), "=&v"(q[3]),           \
                 "=&v"(q[4])                                                   \
               : "v"(addr))

// B-window dword reads for MFMA tiles 0..3 (5 dwords per tile), one wait.
#define DSB_G4(q00,q01,q02,q10,q11,q12,q20,q21,q22,q30,q31,q32, addr)          \
  asm volatile("ds_read2_b32 %0, %12 offset0:0 offset1:1\n\t"                  \
               "ds_read2_b32 %1, %12 offset0:2 offset1:3\n\t"                  \
               "ds_read_b32  %2, %12 offset:16\n\t"                            \
               "ds_read2_b32 %3, %12 offset0:8 offset1:9\n\t"                  \
               "ds_read2_b32 %4, %12 offset0:10 offset1:11\n\t"                \
               "ds_read_b32  %5, %12 offset:48\n\t"                            \
               "ds_read2_b32 %6, %12 offset0:16 offset1:17\n\t"                \
               "ds_read2_b32 %7, %12 offset0:18 offset1:19\n\t"                \
               "ds_read_b32  %8, %12 offset:80\n\t"                            \
               "ds_read2_b32 %9, %12 offset0:24 offset1:25\n\t"                \
               "ds_read2_b32 %10, %12 offset0:26 offset1:27\n\t"               \
               "ds_read_b32  %11, %12 offset:112\n\t"                          \
               "s_waitcnt lgkmcnt(0)"                                          \
               : "=&v"(q00),"=&v"(q01),"=&v"(q02),"=&v"(q10),"=&v"(q11),       \
                 "=&v"(q12),"=&v"(q20),"=&v"(q21),"=&v"(q22),"=&v"(q30),       \
                 "=&v"(q31),"=&v"(q32)                                         \
               : "v"(addr))

// Tiles 4..6.
#define DSB_G3(q40,q41,q42,q50,q51,q52,q60,q61,q62, addr)                      \
  asm volatile("ds_read2_b32 %0, %9 offset0:32 offset1:33\n\t"                 \
               "ds_read2_b32 %1, %9 offset0:34 offset1:35\n\t"                 \
               "ds_read_b32  %2, %9 offset:144\n\t"                            \
               "ds_read2_b32 %3, %9 offset0:40 offset1:41\n\t"                 \
               "ds_read2_b32 %4, %9 offset0:42 offset1:43\n\t"                 \
               "ds_read_b32  %5, %9 offset:176\n\t"                            \
               "ds_read2_b32 %6, %9 offset0:48 offset1:49\n\t"                 \
               "ds_read2_b32 %7, %9 offset0:50 offset1:51\n\t"                 \
               "ds_read_b32  %8, %9 offset:208\n\t"                            \
               "s_waitcnt lgkmcnt(0)"                                          \
               : "=&v"(q40),"=&v"(q41),"=&v"(q42),"=&v"(q50),"=&v"(q51),       \
                 "=&v"(q52),"=&v"(q60),"=&v"(q61),"=&v"(q62)                   \
               : "v"(addr))

#define DSRD6(r0,r1,r2,r3,r4,r5, addr)                                         \
  asm volatile("ds_read_b32 %0, %6 offset:0\n\t"                               \
               "ds_read_b32 %1, %6 offset:216\n\t"                             \
               "ds_read_b32 %2, %6 offset:432\n\t"                             \
               "ds_read_b32 %3, %6 offset:648\n\t"                             \
               "ds_read_b32 %4, %6 offset:864\n\t"                             \
               "ds_read_b32 %5, %6 offset:1080\n\t"                            \
               "s_waitcnt lgkmcnt(0)"                                          \
               : "=&v"(r0),"=&v"(r1),"=&v"(r2),"=&v"(r3),"=&v"(r4),"=&v"(r5)   \
               : "v"(addr))

#define DSW64(addr, val)  asm volatile("ds_write_b64 %0, %1" :: "v"(addr), "v"(val))
#define DSW32(addr, val)  asm volatile("ds_write_b32 %0, %1" :: "v"(addr), "v"(val))

__device__ __forceinline__ unsigned short f2bf(float f) {   // RNE f32->bf16
    unsigned u = __builtin_bit_cast(unsigned, f);
    return (unsigned short)((u + 0x7fffu + ((u >> 16) & 1u)) >> 16);
}

// ---- compile-time window element accessors (phases B/C, unchanged R15) ----
template<int J>
__device__ __forceinline__ float el21(const float4 (&W)[5], float g) {
    if constexpr (J >= 20) return g;
    else {
        constexpr int q = J >> 2, r = J & 3;
        if constexpr (r == 0) return W[q].x;
        else if constexpr (r == 1) return W[q].y;
        else if constexpr (r == 2) return W[q].z;
        else return W[q].w;
    }
}
template<int J>
__device__ __forceinline__ float el24(const float4 (&W)[6]) {
    constexpr int q = J >> 2, r = J & 3;
    if constexpr (r == 0) return W[q].x;
    else if constexpr (r == 1) return W[q].y;
    else if constexpr (r == 2) return W[q].z;
    else return W[q].w;
}
template<int K0>
__device__ __forceinline__ void fq2(const float4 wq, const float4 (&W)[5], float g,
                                    float& a0, float& a1) {
    a0 = fmaf(el21<K0 + 0>(W, g), wq.x, a0); a1 = fmaf(el21<K0 + 1>(W, g), wq.x, a1);
    a0 = fmaf(el21<K0 + 1>(W, g), wq.y, a0); a1 = fmaf(el21<K0 + 2>(W, g), wq.y, a1);
    a0 = fmaf(el21<K0 + 2>(W, g), wq.z, a0); a1 = fmaf(el21<K0 + 3>(W, g), wq.z, a1);
    a0 = fmaf(el21<K0 + 3>(W, g), wq.w, a0); a1 = fmaf(el21<K0 + 4>(W, g), wq.w, a1);
}
template<int K0>
__device__ __forceinline__ void fq4(const float4 wq, const float4 (&W)[6], float (&a)[4]) {
    a[0] = fmaf(el24<K0 + 0>(W), wq.x, a[0]); a[1] = fmaf(el24<K0 + 1>(W), wq.x, a[1]);
    a[2] = fmaf(el24<K0 + 2>(W), wq.x, a[2]); a[3] = fmaf(el24<K0 + 3>(W), wq.x, a[3]);
    a[0] = fmaf(el24<K0 + 1>(W), wq.y, a[0]); a[1] = fmaf(el24<K0 + 2>(W), wq.y, a[1]);
    a[2] = fmaf(el24<K0 + 3>(W), wq.y, a[2]); a[3] = fmaf(el24<K0 + 4>(W), wq.y, a[3]);
    a[0] = fmaf(el24<K0 + 2>(W), wq.z, a[0]); a[1] = fmaf(el24<K0 + 3>(W), wq.z, a[1]);
    a[2] = fmaf(el24<K0 + 4>(W), wq.z, a[2]); a[3] = fmaf(el24<K0 + 5>(W), wq.z, a[3]);
    a[0] = fmaf(el24<K0 + 3>(W), wq.w, a[0]); a[1] = fmaf(el24<K0 + 4>(W), wq.w, a[1]);
    a[2] = fmaf(el24<K0 + 5>(W), wq.w, a[2]); a[3] = fmaf(el24<K0 + 6>(W), wq.w, a[3]);
}
#define FQ2ALL(Q, W, g, a0, a1)                                                \
  do { fq2<0>(Q[0], W, g, a0, a1);  fq2<4>(Q[1], W, g, a0, a1);                \
       fq2<8>(Q[2], W, g, a0, a1);  fq2<12>(Q[3], W, g, a0, a1);               \
       fq2<16>(Q[4], W, g, a0, a1); } while (0)

// 5 dwords (d0..d4) -> shifted bf16x8 window via alignbit (shf = 0 or 16).
#define MK_B(bb, p0, p1, p2)                                                   \
  do {                                                                         \
    const int _d0 = __builtin_bit_cast(int, (p0).x);                           \
    const int _d1 = __builtin_bit_cast(int, (p0).y);                           \
    const int _d2 = __builtin_bit_cast(int, (p1).x);                           \
    const int _d3 = __builtin_bit_cast(int, (p1).y);                           \
    const int _d4 = __builtin_bit_cast(int, (p2));                             \
    i32x4 _b = { (int)__builtin_amdgcn_alignbit((unsigned)_d1, (unsigned)_d0, (unsigned)shf), \
                 (int)__builtin_amdgcn_alignbit((unsigned)_d2, (unsigned)_d1, (unsigned)shf), \
                 (int)__builtin_amdgcn_alignbit((unsigned)_d3, (unsigned)_d2, (unsigned)shf), \
                 (int)__builtin_amdgcn_alignbit((unsigned)_d4, (unsigned)_d3, (unsigned)shf) }; \
    bb = __builtin_bit_cast(bf16x8, _b);                                       \
  } while (0)

#define MFMA(A, B, C) __builtin_amdgcn_mfma_f32_16x16x32_bf16((A), (B), (C), 0, 0, 0)

// one input channel of phase D: 21 dword reads, 7 MFMAs into t0..t6
#define D_CH(AF, CH)                                                           \
  do {                                                                         \
    const unsigned ab = oneb_b + (unsigned)(CH) * 288u + sdw4;                 \
    float2 q00,q01,q10,q11,q20,q21,q30,q31; float q02,q12,q22,q32;             \
    DSB_G4(q00,q01,q02,q10,q11,q12,q20,q21,q22,q30,q31,q32, ab);               \
    bf16x8 bb;                                                                 \
    MK_B(bb, q00, q01, q02); t0 = MFMA(AF, bb, t0);                            \
    MK_B(bb, q10, q11, q12); t1 = MFMA(AF, bb, t1);                            \
    MK_B(bb, q20, q21, q22); t2 = MFMA(AF, bb, t2);                            \
    MK_B(bb, q30, q31, q32); t3 = MFMA(AF, bb, t3);                            \
    float2 q40,q41,q50,q51,q60,q61; float q42,q52,q62;                         \
    DSB_G3(q40,q41,q42,q50,q51,q52,q60,q61,q62, ab);                           \
    MK_B(bb, q40, q41, q42); t4 = MFMA(AF, bb, t4);                            \
    MK_B(bb, q50, q51, q52); t5 = MFMA(AF, bb, t5);                            \
    MK_B(bb, q60, q61, q62); t6 = MFMA(AF, bb, t6);                            \
  } while (0)

// extract tile T: shuffle-pool pairs, +bias, relu, write pooled LDS
#define EX_TILE(CT, T)                                                         \
  do {                                                                         \
    _Pragma("unroll")                                                          \
    for (int j = 0; j < 4; ++j) {                                              \
      const float v = (CT)[j];                                                 \
      const float w = __shfl_xor(v, 1);                                        \
      const float m = fmaxf(fmaxf(v, w) + vb[j], 0.f);                         \
      const int c2i = ((lane >> 4) << 2) + j;                                  \
      if (!(lane & 1) && c2i < 6 && ((T) < 6 || (lane & 15) < 12))             \
        DSW32(poolw + (unsigned)(j * 216 + (T) * 32), m);                      \
    }                                                                          \
  } while (0)

// -------- Kernel 1: A/B/C per R15 (f32), phase D via bf16 MFMA --------
__global__ __launch_bounds__(256, 4) void atom_kernel(
    const float* __restrict__ oh_g,    // [M0,92]
    const float* __restrict__ env_g,   // [M0,55]
    const int*   __restrict__ idx_g,   // [M0] sorted
    const float* __restrict__ wA, const float* __restrict__ bA,  // [3*20],[3]
    const float* __restrict__ w1, const float* __restrict__ b1,  // [3*20],[3]
    const float* __restrict__ w2, const float* __restrict__ b2,  // [6*3*20],[6]
    float* __restrict__ sums,          // [NC,324]
    float* __restrict__ counts)        // [NC]
{
    __shared__ __align__(16) float w_lds[120];            // wA[0:60] w1 at 240B
    __shared__ __align__(16) float s_total[4][280];
    __shared__ __align__(16) float s_oh[4][96];           // one-hot scratch
    __shared__ __align__(16) unsigned short s_oneb[4][432]; // bf16 [3][144]
    __shared__ __align__(16) float s_pool[4][324];        // pooled [6][54]

    const int wave = threadIdx.x >> 6;
    const int lane = threadIdx.x & 63;
    const int tid  = threadIdx.x;

    const unsigned w_b    = (unsigned)(size_t)w_lds;
    const unsigned tot_b  = (unsigned)(size_t)&s_total[wave][0];
    const unsigned oh_b   = (unsigned)(size_t)&s_oh[wave][0];
    const unsigned oneb_b = (unsigned)(size_t)&s_oneb[wave][0];
    const unsigned pool_b = (unsigned)(size_t)&s_pool[wave][0];
    const unsigned lane8  = (unsigned)lane * 8u;
    const unsigned lane16 = (unsigned)lane * 16u;

    // ---- stage conv weights (wA,w1) into LDS once per block ----
    if (tid < 60)       DSW32(w_b + (unsigned)tid * 4u, wA[tid]);
    else if (tid < 120) DSW32(w_b + 240u + (unsigned)(tid - 60) * 4u, w1[tid - 60]);
    __syncthreads();

    // ---- per-wave constants for MFMA phase D ----
    const int s0  = (lane & 15) + ((lane >> 4) << 3);   // window start (elem)
    const int shf = (s0 & 1) << 4;                      // alignbit shift
    const unsigned sdw4 = (unsigned)(s0 >> 1) << 2;     // aligned dword byte off
    const unsigned qb4  = (unsigned)((lane & 15) >> 1) << 2;
    const unsigned poolw = pool_b + (unsigned)((lane >> 4) << 2) * 216u + qb4;

    // A-fragments: w2 bf16, rows(c2)=lane&15 (pad>=6), k=(lane>>4)*8+j (pad kk>=20)
    bf16x8 af0{}, af1{}, af2{};
    {
        const int r = lane & 15, kb = (lane >> 4) << 3;
        #pragma unroll
        for (int j = 0; j < 8; ++j) {
            const int kk = kb + j;
            float v0 = 0.f, v1 = 0.f, v2 = 0.f;
            if (r < 6 && kk < 20) {
                v0 = w2[r * 60 + kk];
                v1 = w2[r * 60 + 20 + kk];
                v2 = w2[r * 60 + 40 + kk];
            }
            af0[j] = (short)f2bf(v0);
            af1[j] = (short)f2bf(v1);
            af2[j] = (short)f2bf(v2);
        }
    }
    float vb[4];
    #pragma unroll
    for (int j = 0; j < 4; ++j) {
        const int c2i = ((lane >> 4) << 2) + j;
        float t = 0.f; if (c2i < 6) t = b2[c2i];
        vb[j] = t;
    }
    // zero pads: tot[274..279], oneb rows bytes 256..287 (NaN hygiene for MFMA)
    if (lane < 6)  DSW32(tot_b + (274u + (unsigned)lane) * 4u, 0.f);
    if (lane < 24) DSW32(oneb_b + (unsigned)(lane >> 3) * 288u + 256u +
                         (unsigned)(lane & 7) * 4u, 0.f);

    const int wbase = (blockIdx.x * 4 + wave) * APW;

    float fa[6] = {0.f, 0.f, 0.f, 0.f, 0.f, 0.f};
    float cnt = 0.f;
    int cur = idx_g[wbase];

    for (int it = 0; it < APW; ++it) {
        const int atom = wbase + it;
        const int cry = idx_g[atom];                  // wave-uniform
        if (cry != cur) {                             // uniform branch: flush
            if (lane < 54) {
                float* dst = sums + (size_t)cur * FDIM + lane;
                #pragma unroll
                for (int c2 = 0; c2 < 6; ++c2) {
                    atomicAdd(dst + c2 * 54, fa[c2]);
                    fa[c2] = 0.f;
                }
            }
            if (lane == 0) atomicAdd(&counts[cur], cnt);
            cnt = 0.f;
            cur = cry;
        }

        // ---- Phase A: one-hot (92) + env (55) into LDS ----
        if (lane < 46) {
            const float2 v = *reinterpret_cast<const float2*>(oh_g + (size_t)atom * 92 + 2 * lane);
            DSW64(oh_b + lane8, v);
        }
        if (lane < 55) {
            DSW32(tot_b + (219u + (unsigned)lane) * 4u, env_g[(size_t)atom * 55 + lane]);
        }

        // ---- Phase B: conva -> relu -> total[0..218]  (37 lanes x 2 pos) ----
        if (lane < 37) {
            float4 W[5]; float g;
            DSWIN21(W[0], W[1], W[2], W[3], W[4], g, oh_b + lane8);
            const unsigned p2 = 2u * (unsigned)lane;
            #pragma unroll
            for (int c = 0; c < 3; ++c) {
                float4 wq[5];
                DSWQ5(wq, w_b + (unsigned)c * 80u);
                float a0 = bA[c], a1 = a0;
                FQ2ALL(wq, W, g, a0, a1);
                const unsigned tb = tot_b + (73u * (unsigned)c + p2) * 4u;
                DSW32(tb, fmaxf(a0, 0.f));
                if (p2 + 1 < 73) DSW32(tb + 4u, fmaxf(a1, 0.f));
            }
        }

        // ---- Phase C: conv1 + relu + maxpool2 -> bf16 one1[3][144] ----
        {
            float4 W[6];
            DSWIN24(W[0], W[1], W[2], W[3], W[4], W[5], tot_b + lane16);
            #pragma unroll
            for (int c = 0; c < 3; ++c) {
                float4 wq[5];
                DSWQ5(wq, w_b + 240u + (unsigned)c * 80u);
                float a4[4] = {b1[c], b1[c], b1[c], b1[c]};
                fq4<0>(wq[0], W, a4);  fq4<4>(wq[1], W, a4);  fq4<8>(wq[2], W, a4);
                fq4<12>(wq[3], W, a4); fq4<16>(wq[4], W, a4);
                const float p0 = fmaxf(fmaxf(a4[0], a4[1]), 0.f);
                const float p1 = fmaxf(fmaxf(a4[2], a4[3]), 0.f);
                const unsigned pk = (unsigned)f2bf(p0) | ((unsigned)f2bf(p1) << 16);
                DSW32(oneb_b + (unsigned)c * 288u + (unsigned)lane * 4u,
                      __builtin_bit_cast(float, pk));
            }
        }

        // ---- Phase D: conv2 via MFMA (21 mfma_f32_16x16x32_bf16) ----
        {
            f32x4 t0 = {0,0,0,0}, t1 = {0,0,0,0}, t2 = {0,0,0,0}, t3 = {0,0,0,0},
                  t4 = {0,0,0,0}, t5 = {0,0,0,0}, t6 = {0,0,0,0};
            D_CH(af0, 0);
            D_CH(af1, 1);
            D_CH(af2, 2);
            EX_TILE(t0, 0); EX_TILE(t1, 1); EX_TILE(t2, 2); EX_TILE(t3, 3);
            EX_TILE(t4, 4); EX_TILE(t5, 5); EX_TILE(t6, 6);
            if (lane < 54) {
                float r0, r1, r2, r3, r4, r5;
                DSRD6(r0, r1, r2, r3, r4, r5, pool_b + (unsigned)lane * 4u);
                fa[0] += r0; fa[1] += r1; fa[2] += r2;
                fa[3] += r3; fa[4] += r4; fa[5] += r5;
            }
        }
        cnt += 1.f;
    }

    // ---- final flush ----
    if (lane < 54) {
        float* dst = sums + (size_t)cur * FDIM + lane;
        #pragma unroll
        for (int c2 = 0; c2 < 6; ++c2) atomicAdd(dst + c2 * 54, fa[c2]);
    }
    if (lane == 0) atomicAdd(&counts[cur], cnt);
}

// -------- Kernel 2: per-crystal mean+relu, 324->32 softplus, 32->1 ----------
__global__ __launch_bounds__(64) void head_kernel(
    const float* __restrict__ sums, const float* __restrict__ counts,
    const float* __restrict__ lin_w, const float* __restrict__ lin_b,
    const float* __restrict__ lin1_w, const float* __restrict__ lin1_b,
    float* __restrict__ out)
{
    __shared__ float p[FDIM];
    const int c = blockIdx.x;
    const int lane = threadIdx.x;
    const float inv = 1.0f / fmaxf(counts[c], 1.0f);
    for (int i = lane; i < FDIM; i += 64)
        p[i] = fmaxf(sums[(size_t)c * FDIM + i] * inv, 0.f);
    __syncthreads();

    float r = 0.f;
    if (lane < 32) {
        float acc = lin_b[lane];
        const float* wrow = lin_w + lane * FDIM;
        #pragma unroll 4
        for (int i = 0; i < FDIM; ++i) acc = fmaf(p[i], wrow[i], acc);
        const float sp = (acc > 0.f) ? acc + log1pf(expf(-acc)) : log1pf(expf(acc));
        r = sp * lin1_w[lane];
    }
    #pragma unroll
    for (int off = 16; off; off >>= 1) r += __shfl_down(r, off);
    if (lane == 0) out[c] = r + lin1_b[0];
}

extern "C" void kernel_launch(void* const* d_in, const int* in_sizes, int n_in,
                              void* d_out, int out_size, void* d_ws, size_t ws_size,
                              hipStream_t stream) {
    (void)in_sizes; (void)n_in; (void)out_size; (void)ws_size;
    const float* oh    = (const float*)d_in[0];
    const float* env   = (const float*)d_in[1];
    const int*   idx   = (const int*)  d_in[2];
    // d_in[3] = num_segments (constant 4096)
    const float* wA    = (const float*)d_in[4];
    const float* bA    = (const float*)d_in[5];
    const float* w1    = (const float*)d_in[6];
    const float* b1    = (const float*)d_in[7];
    const float* w2    = (const float*)d_in[8];
    const float* b2    = (const float*)d_in[9];
    const float* lin_w = (const float*)d_in[10];
    const float* lin_b = (const float*)d_in[11];
    const float* lin1_w= (const float*)d_in[12];
    const float* lin1_b= (const float*)d_in[13];

    float* sums   = (float*)d_ws;             // [NC*FDIM]
    float* counts = sums + (size_t)NC * FDIM; // [NC]

    hipMemsetAsync(d_ws, 0, ((size_t)NC * FDIM + NC) * sizeof(float), stream);

    // 8192 blocks x 4 waves x 4 atoms = M0
    atom_kernel<<<M0 / 16, 256, 0, stream>>>(oh, env, idx, wA, bA, w1, b1,
                                             w2, b2, sums, counts);
    head_kernel<<<NC, 64, 0, stream>>>(sums, counts, lin_w, lin_b, lin1_w, lin1_b,
                                       (float*)d_out);
}

// Round 23
// 247.407 us; speedup vs baseline: 1.4511x; 1.4511x over previous
//
#include <hip/hip_runtime.h>
#include <math.h>

#define M0 131072
#define NC 4096
#define FDIM 324   // 6*54
#define APW 4      // atoms per wave (sorted idx -> mostly same crystal)

// ---- batched asm LDS ops, wait INSIDE each block (proven-correct R12/R15 form)
#define DSWIN21(w0, w1, w2, w3, w4, g, addr)                                   \
  asm volatile("ds_read2_b64 %0, %6 offset0:0 offset1:1\n\t"                   \
               "ds_read2_b64 %1, %6 offset0:2 offset1:3\n\t"                   \
               "ds_read2_b64 %2, %6 offset0:4 offset1:5\n\t"                   \
               "ds_read2_b64 %3, %6 offset0:6 offset1:7\n\t"                   \
               "ds_read2_b64 %4, %6 offset0:8 offset1:9\n\t"                   \
               "ds_read_b32 %5, %6 offset:80\n\t"                              \
               "s_waitcnt lgkmcnt(0)"                                          \
               : "=v"(w0), "=v"(w1), "=v"(w2), "=v"(w3), "=v"(w4), "=v"(g)     \
               : "v"(addr))

#define DSWIN24(w0, w1, w2, w3, w4, w5, addr)                                  \
  asm volatile("ds_read_b128 %0, %6 offset:0\n\t"                              \
               "ds_read_b128 %1, %6 offset:16\n\t"                             \
               "ds_read_b128 %2, %6 offset:32\n\t"                             \
               "ds_read_b128 %3, %6 offset:48\n\t"                             \
               "ds_read_b128 %4, %6 offset:64\n\t"                             \
               "ds_read_b128 %5, %6 offset:80\n\t"                             \
               "s_waitcnt lgkmcnt(0)"                                          \
               : "=v"(w0), "=v"(w1), "=v"(w2), "=v"(w3), "=v"(w4), "=v"(w5)    \
               : "v"(addr))

#define DSWQ5(q, addr)                                                         \
  asm volatile("ds_read_b128 %0, %5 offset:0\n\t"                              \
               "ds_read_b128 %1, %5 offset:16\n\t"                             \
               "ds_read_b128 %2, %5 offset:32\n\t"                             \
               "ds_read_b128 %3, %5 offset:48\n\t"                             \
               "ds_read_b128 %4, %5 offset:64\n\t"                             \
               "s_waitcnt lgkmcnt(0)"                                          \
               : "=v"(q[0]), "=v"(q[1]), "=v"(q[2]), "=v"(q[3]), "=v"(q[4])    \
               : "v"(addr))

#define DSW64(addr, val)  asm volatile("ds_write_b64 %0, %1" :: "v"(addr), "v"(val))
#define DSW32(addr, val)  asm volatile("ds_write_b32 %0, %1" :: "v"(addr), "v"(val))

// ---- compile-time window element accessors ----
template<int J>
__device__ __forceinline__ float el21(const float4 (&W)[5], float g) {
    if constexpr (J >= 20) return g;
    else {
        constexpr int q = J >> 2, r = J & 3;
        if constexpr (r == 0) return W[q].x;
        else if constexpr (r == 1) return W[q].y;
        else if constexpr (r == 2) return W[q].z;
        else return W[q].w;
    }
}
template<int J>
__device__ __forceinline__ float el24(const float4 (&W)[6]) {
    constexpr int q = J >> 2, r = J & 3;
    if constexpr (r == 0) return W[q].x;
    else if constexpr (r == 1) return W[q].y;
    else if constexpr (r == 2) return W[q].z;
    else return W[q].w;
}

template<int K0>
__device__ __forceinline__ void fq2(const float4 wq, const float4 (&W)[5], float g,
                                    float& a0, float& a1) {
    a0 = fmaf(el21<K0 + 0>(W, g), wq.x, a0); a1 = fmaf(el21<K0 + 1>(W, g), wq.x, a1);
    a0 = fmaf(el21<K0 + 1>(W, g), wq.y, a0); a1 = fmaf(el21<K0 + 2>(W, g), wq.y, a1);
    a0 = fmaf(el21<K0 + 2>(W, g), wq.z, a0); a1 = fmaf(el21<K0 + 3>(W, g), wq.z, a1);
    a0 = fmaf(el21<K0 + 3>(W, g), wq.w, a0); a1 = fmaf(el21<K0 + 4>(W, g), wq.w, a1);
}
template<int K0>
__device__ __forceinline__ void fq4(const float4 wq, const float4 (&W)[6], float (&a)[4]) {
    a[0] = fmaf(el24<K0 + 0>(W), wq.x, a[0]); a[1] = fmaf(el24<K0 + 1>(W), wq.x, a[1]);
    a[2] = fmaf(el24<K0 + 2>(W), wq.x, a[2]); a[3] = fmaf(el24<K0 + 3>(W), wq.x, a[3]);
    a[0] = fmaf(el24<K0 + 1>(W), wq.y, a[0]); a[1] = fmaf(el24<K0 + 2>(W), wq.y, a[1]);
    a[2] = fmaf(el24<K0 + 3>(W), wq.y, a[2]); a[3] = fmaf(el24<K0 + 4>(W), wq.y, a[3]);
    a[0] = fmaf(el24<K0 + 2>(W), wq.z, a[0]); a[1] = fmaf(el24<K0 + 3>(W), wq.z, a[1]);
    a[2] = fmaf(el24<K0 + 4>(W), wq.z, a[2]); a[3] = fmaf(el24<K0 + 5>(W), wq.z, a[3]);
    a[0] = fmaf(el24<K0 + 3>(W), wq.w, a[0]); a[1] = fmaf(el24<K0 + 4>(W), wq.w, a[1]);
    a[2] = fmaf(el24<K0 + 5>(W), wq.w, a[2]); a[3] = fmaf(el24<K0 + 6>(W), wq.w, a[3]);
}

// -------- Kernel 1: per-atom conv pipeline + register segment accumulation ----
// R15 structure verbatim; ONLY change: bijective XCD-chunk blockIdx swizzle so
// same-crystal atomic lines stay in one XCD's L2 (cuts HBM write-through).
__global__ __launch_bounds__(256, 8) void atom_kernel(
    const float* __restrict__ oh_g,    // [M0,92]
    const float* __restrict__ env_g,   // [M0,55]
    const int*   __restrict__ idx_g,   // [M0] sorted
    const float* __restrict__ wA, const float* __restrict__ bA,  // [3*20],[3]
    const float* __restrict__ w1, const float* __restrict__ b1,  // [3*20],[3]
    const float* __restrict__ w2, const float* __restrict__ b2,  // [6*3*20],[6]
    float* __restrict__ sums,          // [NC,324]
    float* __restrict__ counts)        // [NC]
{
    __shared__ __align__(16) float w_lds[480];        // wA[0:60] w1[60:120] w2[120:480]
    __shared__ __align__(16) float s_total[4][280];   // concat(atom[219], env[55])
    __shared__ __align__(16) float s_one1[4][384];    // conv1 pooled [3][128]; first 92 = oh scratch

    // XCD-chunk swizzle (bijective: 8192 % 8 == 0): contiguous atom ranges per XCD.
    const int bid = (blockIdx.x & 7) * 1024 + (blockIdx.x >> 3);

    const int wave = threadIdx.x >> 6;
    const int lane = threadIdx.x & 63;
    const int tid  = threadIdx.x;

    const unsigned w_b   = (unsigned)(size_t)w_lds;
    const unsigned wD_b  = w_b + 480u;                // w2 bytes
    const unsigned tot_b = (unsigned)(size_t)&s_total[wave][0];
    const unsigned one_b = (unsigned)(size_t)&s_one1[wave][0];
    const unsigned oh_b  = one_b;                     // scratch alias

    // ---- stage all conv weights into LDS once per block (asm writes: no DCE) ----
    for (int i = tid; i < 360; i += 256) DSW32(w_b + (120u + (unsigned)i) * 4u, w2[i]);
    if (tid < 60)       DSW32(w_b + (unsigned)tid * 4u, wA[tid]);
    else if (tid < 120) DSW32(w_b + (unsigned)tid * 4u, w1[tid - 60]);
    __syncthreads();

    const int wbase = (bid * 4 + wave) * APW;

    float fa[6] = {0.f, 0.f, 0.f, 0.f, 0.f, 0.f};
    float cnt = 0.f;
    int cur = idx_g[wbase];

    for (int it = 0; it < APW; ++it) {
        const int atom = wbase + it;
        const int cry = idx_g[atom];                  // wave-uniform
        if (cry != cur) {                             // uniform branch: flush
            if (lane < 54) {
                float* dst = sums + (size_t)cur * FDIM + lane;
                #pragma unroll
                for (int c2 = 0; c2 < 6; ++c2) {
                    atomicAdd(dst + c2 * 54, fa[c2]);
                    fa[c2] = 0.f;
                }
            }
            if (lane == 0) atomicAdd(&counts[cur], cnt);
            cnt = 0.f;
            cur = cry;
        }

        // ---- Phase A: one-hot (92) + env (55) into LDS ----
        if (lane < 46) {
            const float2 v = *reinterpret_cast<const float2*>(oh_g + (size_t)atom * 92 + 2 * lane);
            DSW64(oh_b + (unsigned)lane * 8u, v);
        }
        if (lane < 55) {
            DSW32(tot_b + (219u + (unsigned)lane) * 4u, env_g[(size_t)atom * 55 + lane]);
        }

        // ---- Phase B: conva -> relu -> total[0..218]  (37 lanes x 2 pos) ----
        if (lane < 37) {
            float4 W[5]; float g;
            DSWIN21(W[0], W[1], W[2], W[3], W[4], g, oh_b + (unsigned)lane * 8u);
            const unsigned p2 = 2u * (unsigned)lane;
            #pragma unroll
            for (int c = 0; c < 3; ++c) {
                float4 wq[5];
                DSWQ5(wq, w_b + (unsigned)c * 80u);
                float a0 = bA[c], a1 = a0;
                fq2<0>(wq[0], W, g, a0, a1);  fq2<4>(wq[1], W, g, a0, a1);
                fq2<8>(wq[2], W, g, a0, a1);  fq2<12>(wq[3], W, g, a0, a1);
                fq2<16>(wq[4], W, g, a0, a1);
                const unsigned tb = tot_b + (73u * (unsigned)c + p2) * 4u;
                DSW32(tb, fmaxf(a0, 0.f));
                if (p2 + 1 < 73) DSW32(tb + 4u, fmaxf(a1, 0.f));
            }
        }

        // ---- Phase C: conv1 + relu + maxpool2 -> one1[3][128] (64 lanes x 4 pos) ----
        // lane q: unpooled 4q..4q+3 -> pooled {2q,2q+1}; q=63 garbage -> dead slot 127.
        {
            float4 W[6];
            DSWIN24(W[0], W[1], W[2], W[3], W[4], W[5], tot_b + (unsigned)lane * 16u);
            #pragma unroll
            for (int c = 0; c < 3; ++c) {
                float4 wq[5];
                DSWQ5(wq, w_b + 240u + (unsigned)c * 80u);
                float a4[4] = {b1[c], b1[c], b1[c], b1[c]};
                fq4<0>(wq[0], W, a4);  fq4<4>(wq[1], W, a4);  fq4<8>(wq[2], W, a4);
                fq4<12>(wq[3], W, a4); fq4<16>(wq[4], W, a4);
                float2 st;
                st.x = fmaxf(fmaxf(a4[0], a4[1]), 0.f);
                st.y = fmaxf(fmaxf(a4[2], a4[3]), 0.f);
                DSW64(one_b + ((unsigned)c * 128u + 2u * (unsigned)lane) * 4u, st);
            }
        }

        // ---- Phase D: conv2 + relu + maxpool2 -> fa[6] accumulate (54 lanes) ----
        if (lane < 54) {
            float acc0[6], acc1[6];
            #pragma unroll
            for (int c2 = 0; c2 < 6; ++c2) { acc0[c2] = b2[c2]; acc1[c2] = acc0[c2]; }
            #pragma unroll
            for (int ch = 0; ch < 3; ++ch) {
                float4 W[5]; float g;
                DSWIN21(W[0], W[1], W[2], W[3], W[4], g,
                        one_b + (unsigned)ch * 512u + (unsigned)lane * 8u);
                #pragma unroll
                for (int c2 = 0; c2 < 6; ++c2) {
                    float4 wq[5];
                    DSWQ5(wq, wD_b + ((unsigned)c2 * 3u + (unsigned)ch) * 80u);
                    fq2<0>(wq[0], W, g, acc0[c2], acc1[c2]);
                    fq2<4>(wq[1], W, g, acc0[c2], acc1[c2]);
                    fq2<8>(wq[2], W, g, acc0[c2], acc1[c2]);
                    fq2<12>(wq[3], W, g, acc0[c2], acc1[c2]);
                    fq2<16>(wq[4], W, g, acc0[c2], acc1[c2]);
                }
            }
            #pragma unroll
            for (int c2 = 0; c2 < 6; ++c2)
                fa[c2] += fmaxf(fmaxf(acc0[c2], acc1[c2]), 0.f);
        }
        cnt += 1.f;
    }

    // ---- final flush ----
    if (lane < 54) {
        float* dst = sums + (size_t)cur * FDIM + lane;
        #pragma unroll
        for (int c2 = 0; c2 < 6; ++c2) atomicAdd(dst + c2 * 54, fa[c2]);
    }
    if (lane == 0) atomicAdd(&counts[cur], cnt);
}

// -------- Kernel 2: per-crystal mean+relu, 324->32 softplus, 32->1 ----------
__global__ __launch_bounds__(64) void head_kernel(
    const float* __restrict__ sums, const float* __restrict__ counts,
    const float* __restrict__ lin_w, const float* __restrict__ lin_b,
    const float* __restrict__ lin1_w, const float* __restrict__ lin1_b,
    float* __restrict__ out)
{
    __shared__ float p[FDIM];
    const int c = blockIdx.x;
    const int lane = threadIdx.x;
    const float inv = 1.0f / fmaxf(counts[c], 1.0f);
    for (int i = lane; i < FDIM; i += 64)
        p[i] = fmaxf(sums[(size_t)c * FDIM + i] * inv, 0.f);
    __syncthreads();

    float r = 0.f;
    if (lane < 32) {
        float acc = lin_b[lane];
        const float* wrow = lin_w + lane * FDIM;
        #pragma unroll 4
        for (int i = 0; i < FDIM; ++i) acc = fmaf(p[i], wrow[i], acc);
        const float sp = (acc > 0.f) ? acc + log1pf(expf(-acc)) : log1pf(expf(acc));
        r = sp * lin1_w[lane];
    }
    #pragma unroll
    for (int off = 16; off; off >>= 1) r += __shfl_down(r, off);
    if (lane == 0) out[c] = r + lin1_b[0];
}

extern "C" void kernel_launch(void* const* d_in, const int* in_sizes, int n_in,
                              void* d_out, int out_size, void* d_ws, size_t ws_size,
                              hipStream_t stream) {
    (void)in_sizes; (void)n_in; (void)out_size; (void)ws_size;
    const float* oh    = (const float*)d_in[0];
    const float* env   = (const float*)d_in[1];
    const int*   idx   = (const int*)  d_in[2];
    // d_in[3] = num_segments (constant 4096)
    const float* wA    = (const float*)d_in[4];
    const float* bA    = (const float*)d_in[5];
    const float* w1    = (const float*)d_in[6];
    const float* b1    = (const float*)d_in[7];
    const float* w2    = (const float*)d_in[8];
    const float* b2    = (const float*)d_in[9];
    const float* lin_w = (const float*)d_in[10];
    const float* lin_b = (const float*)d_in[11];
    const float* lin1_w= (const float*)d_in[12];
    const float* lin1_b= (const float*)d_in[13];

    float* sums   = (float*)d_ws;             // [NC*FDIM]
    float* counts = sums + (size_t)NC * FDIM; // [NC]

    hipMemsetAsync(d_ws, 0, ((size_t)NC * FDIM + NC) * sizeof(float), stream);

    // 8192 blocks x 4 waves x 4 atoms = M0
    atom_kernel<<<M0 / 16, 256, 0, stream>>>(oh, env, idx, wA, bA, w1, b1,
                                             w2, b2, sums, counts);
    head_kernel<<<NC, 64, 0, stream>>>(sums, counts, lin_w, lin_b, lin1_w, lin1_b,
                                       (float*)d_out);
}

// Round 25
// 210.534 us; speedup vs baseline: 1.7052x; 1.1751x over previous
//
#include <hip/hip_runtime.h>
#include <math.h>

#define M0 131072
#define NC 4096
#define FDIM 324   // 6*54
#define APW 4      // atoms per wave (sorted idx -> mostly same crystal)

typedef __attribute__((ext_vector_type(2))) __fp16 h16x2;   // matches cvt_pkrtz

#define PKRTZ(a, b) __builtin_amdgcn_cvt_pkrtz((a), (b))
#if defined(__has_builtin)
#if __has_builtin(__builtin_amdgcn_fdot2)
#define FDOT2(a, b, c) __builtin_amdgcn_fdot2((a), (b), (c), false)
#endif
#endif
#ifndef FDOT2
__device__ __forceinline__ float fdot2f(h16x2 a, h16x2 b, float c) {
    return (float)a.x * (float)b.x + (float)a.y * (float)b.y + c;
}
#define FDOT2(a, b, c) fdot2f((a), (b), (c))
#endif
#define BCH(u) __builtin_bit_cast(h16x2, (u))

// ---- DS reads, wait INSIDE block; ALL outputs early-clobber (R21 lesson) ----
#define DSWIN21(w0, w1, w2, w3, w4, g, addr)                                   \
  asm volatile("ds_read2_b64 %0, %6 offset0:0 offset1:1\n\t"                   \
               "ds_read2_b64 %1, %6 offset0:2 offset1:3\n\t"                   \
               "ds_read2_b64 %2, %6 offset0:4 offset1:5\n\t"                   \
               "ds_read2_b64 %3, %6 offset0:6 offset1:7\n\t"                   \
               "ds_read2_b64 %4, %6 offset0:8 offset1:9\n\t"                   \
               "ds_read_b32 %5, %6 offset:80\n\t"                              \
               "s_waitcnt lgkmcnt(0)"                                          \
               : "=&v"(w0), "=&v"(w1), "=&v"(w2), "=&v"(w3), "=&v"(w4),        \
                 "=&v"(g)                                                      \
               : "v"(addr))

#define DSWIN24(w0, w1, w2, w3, w4, w5, addr)                                  \
  asm volatile("ds_read_b128 %0, %6 offset:0\n\t"                              \
               "ds_read_b128 %1, %6 offset:16\n\t"                             \
               "ds_read_b128 %2, %6 offset:32\n\t"                             \
               "ds_read_b128 %3, %6 offset:48\n\t"                             \
               "ds_read_b128 %4, %6 offset:64\n\t"                             \
               "ds_read_b128 %5, %6 offset:80\n\t"                             \
               "s_waitcnt lgkmcnt(0)"                                          \
               : "=&v"(w0), "=&v"(w1), "=&v"(w2), "=&v"(w3), "=&v"(w4),        \
                 "=&v"(w5)                                                     \
               : "v"(addr))

// 10 packed-f16x2 weight dwords (one conv row), one wait.
#define DSWH10(q0, q1, q2, addr)                                               \
  asm volatile("ds_read_b128 %0, %3 offset:0\n\t"                              \
               "ds_read_b128 %1, %3 offset:16\n\t"                             \
               "ds_read_b64 %2, %3 offset:32\n\t"                              \
               "s_waitcnt lgkmcnt(0)"                                          \
               : "=&v"(q0), "=&v"(q1), "=&v"(q2)                               \
               : "v"(addr))

#define DSW64(addr, val)  asm volatile("ds_write_b64 %0, %1" :: "v"(addr), "v"(val))
#define DSW32(addr, val)  asm volatile("ds_write_b32 %0, %1" :: "v"(addr), "v"(val))

// ---- compile-time window element accessors ----
template<int J>
__device__ __forceinline__ float el21(const float4 (&W)[5], float g) {
    if constexpr (J >= 20) return g;
    else {
        constexpr int q = J >> 2, r = J & 3;
        if constexpr (r == 0) return W[q].x;
        else if constexpr (r == 1) return W[q].y;
        else if constexpr (r == 2) return W[q].z;
        else return W[q].w;
    }
}
template<int J>
__device__ __forceinline__ float el24(const float4 (&W)[6]) {
    constexpr int q = J >> 2, r = J & 3;
    if constexpr (r == 0) return W[q].x;
    else if constexpr (r == 1) return W[q].y;
    else if constexpr (r == 2) return W[q].z;
    else return W[q].w;
}

// pack 21-window into even/odd f16x2 pair streams (10 each)
#define CVT21(ev, od, W, g) do {                                               \
  ev[0]=PKRTZ(el21<0>(W,g),el21<1>(W,g));   od[0]=PKRTZ(el21<1>(W,g),el21<2>(W,g));   \
  ev[1]=PKRTZ(el21<2>(W,g),el21<3>(W,g));   od[1]=PKRTZ(el21<3>(W,g),el21<4>(W,g));   \
  ev[2]=PKRTZ(el21<4>(W,g),el21<5>(W,g));   od[2]=PKRTZ(el21<5>(W,g),el21<6>(W,g));   \
  ev[3]=PKRTZ(el21<6>(W,g),el21<7>(W,g));   od[3]=PKRTZ(el21<7>(W,g),el21<8>(W,g));   \
  ev[4]=PKRTZ(el21<8>(W,g),el21<9>(W,g));   od[4]=PKRTZ(el21<9>(W,g),el21<10>(W,g));  \
  ev[5]=PKRTZ(el21<10>(W,g),el21<11>(W,g)); od[5]=PKRTZ(el21<11>(W,g),el21<12>(W,g)); \
  ev[6]=PKRTZ(el21<12>(W,g),el21<13>(W,g)); od[6]=PKRTZ(el21<13>(W,g),el21<14>(W,g)); \
  ev[7]=PKRTZ(el21<14>(W,g),el21<15>(W,g)); od[7]=PKRTZ(el21<15>(W,g),el21<16>(W,g)); \
  ev[8]=PKRTZ(el21<16>(W,g),el21<17>(W,g)); od[8]=PKRTZ(el21<17>(W,g),el21<18>(W,g)); \
  ev[9]=PKRTZ(el21<18>(W,g),el21<19>(W,g)); od[9]=PKRTZ(el21<19>(W,g),el21<20>(W,g)); \
} while (0)

// pack 24-window into even/odd streams (11 each; covers 4 positions)
#define CVT24(ev, od, W) do {                                                  \
  ev[0]=PKRTZ(el24<0>(W),el24<1>(W));   od[0]=PKRTZ(el24<1>(W),el24<2>(W));    \
  ev[1]=PKRTZ(el24<2>(W),el24<3>(W));   od[1]=PKRTZ(el24<3>(W),el24<4>(W));    \
  ev[2]=PKRTZ(el24<4>(W),el24<5>(W));   od[2]=PKRTZ(el24<5>(W),el24<6>(W));    \
  ev[3]=PKRTZ(el24<6>(W),el24<7>(W));   od[3]=PKRTZ(el24<7>(W),el24<8>(W));    \
  ev[4]=PKRTZ(el24<8>(W),el24<9>(W));   od[4]=PKRTZ(el24<9>(W),el24<10>(W));   \
  ev[5]=PKRTZ(el24<10>(W),el24<11>(W)); od[5]=PKRTZ(el24<11>(W),el24<12>(W));  \
  ev[6]=PKRTZ(el24<12>(W),el24<13>(W)); od[6]=PKRTZ(el24<13>(W),el24<14>(W));  \
  ev[7]=PKRTZ(el24<14>(W),el24<15>(W)); od[7]=PKRTZ(el24<15>(W),el24<16>(W));  \
  ev[8]=PKRTZ(el24<16>(W),el24<17>(W)); od[8]=PKRTZ(el24<17>(W),el24<18>(W));  \
  ev[9]=PKRTZ(el24<18>(W),el24<19>(W)); od[9]=PKRTZ(el24<19>(W),el24<20>(W));  \
  ev[10]=PKRTZ(el24<20>(W),el24<21>(W)); od[10]=PKRTZ(el24<21>(W),el24<22>(W)); \
} while (0)

#define WPBUILD(wp, q0, q1, q2) do {                                           \
  wp[0]=BCH(q0.x); wp[1]=BCH(q0.y); wp[2]=BCH(q0.z); wp[3]=BCH(q0.w);          \
  wp[4]=BCH(q1.x); wp[5]=BCH(q1.y); wp[6]=BCH(q1.z); wp[7]=BCH(q1.w);          \
  wp[8]=BCH(q2.x); wp[9]=BCH(q2.y);                                            \
} while (0)

// -------- Kernel 1: per-atom conv pipeline with packed-f16 dot2 math --------
__global__ __launch_bounds__(256, 6) void atom_kernel(
    const float* __restrict__ oh_g,    // [M0,92]
    const float* __restrict__ env_g,   // [M0,55]
    const int*   __restrict__ idx_g,   // [M0] sorted
    const float* __restrict__ wA, const float* __restrict__ bA,  // [3*20],[3]
    const float* __restrict__ w1, const float* __restrict__ b1,  // [3*20],[3]
    const float* __restrict__ w2, const float* __restrict__ b2,  // [6*3*20],[6]
    float* __restrict__ sums,          // [NC,324]
    float* __restrict__ counts)        // [NC]
{
    // packed f16x2 weights: B rows @ c*48B, C @ 144+c*48, D @ 288+idx*48 (1152 B)
    __shared__ __align__(16) float w_lds[288];
    __shared__ __align__(16) float s_total[4][280];   // concat(atom[219], env[55])
    __shared__ __align__(16) float s_one1[4][384];    // conv1 pooled [3][128]; first 92 = oh scratch

    // XCD-chunk swizzle (bijective: 8192 % 8 == 0).
    const int bid = (blockIdx.x & 7) * 1024 + (blockIdx.x >> 3);

    const int wave = threadIdx.x >> 6;
    const int lane = threadIdx.x & 63;
    const int tid  = threadIdx.x;

    const unsigned w_b   = (unsigned)(size_t)w_lds;
    const unsigned wD_b  = w_b + 288u;
    const unsigned tot_b = (unsigned)(size_t)&s_total[wave][0];
    const unsigned one_b = (unsigned)(size_t)&s_one1[wave][0];
    const unsigned oh_b  = one_b;                     // scratch alias

    // ---- stage all conv weights into LDS as packed f16x2, once per block ----
    if (tid < 30) {
        const int c = tid / 10, kk = tid % 10;
        const h16x2 p = PKRTZ(wA[c * 20 + 2 * kk], wA[c * 20 + 2 * kk + 1]);
        DSW32(w_b + (unsigned)c * 48u + (unsigned)kk * 4u, __builtin_bit_cast(float, p));
    } else if (tid < 60) {
        const int t = tid - 30, c = t / 10, kk = t % 10;
        const h16x2 p = PKRTZ(w1[c * 20 + 2 * kk], w1[c * 20 + 2 * kk + 1]);
        DSW32(w_b + 144u + (unsigned)c * 48u + (unsigned)kk * 4u, __builtin_bit_cast(float, p));
    }
    if (tid >= 64 && tid < 244) {
        const int j = tid - 64, r = j / 10, kk = j % 10;
        const h16x2 p = PKRTZ(w2[r * 20 + 2 * kk], w2[r * 20 + 2 * kk + 1]);
        DSW32(wD_b + (unsigned)r * 48u + (unsigned)kk * 4u, __builtin_bit_cast(float, p));
    }
    __syncthreads();

    const int wbase = (bid * 4 + wave) * APW;

    float fa[6] = {0.f, 0.f, 0.f, 0.f, 0.f, 0.f};
    float cnt = 0.f;
    int cur = idx_g[wbase];

    for (int it = 0; it < APW; ++it) {
        const int atom = wbase + it;
        const int cry = idx_g[atom];                  // wave-uniform
        if (cry != cur) {                             // uniform branch: flush
            if (lane < 54) {
                float* dst = sums + (size_t)cur * FDIM + lane;
                #pragma unroll
                for (int c2 = 0; c2 < 6; ++c2) {
                    atomicAdd(dst + c2 * 54, fa[c2]);
                    fa[c2] = 0.f;
                }
            }
            if (lane == 0) atomicAdd(&counts[cur], cnt);
            cnt = 0.f;
            cur = cry;
        }

        // ---- Phase A: one-hot (92) + env (55) into LDS ----
        if (lane < 46) {
            const float2 v = *reinterpret_cast<const float2*>(oh_g + (size_t)atom * 92 + 2 * lane);
            DSW64(oh_b + (unsigned)lane * 8u, v);
        }
        if (lane < 55) {
            DSW32(tot_b + (219u + (unsigned)lane) * 4u, env_g[(size_t)atom * 55 + lane]);
        }

        // ---- Phase B: conva -> relu -> total[0..218]  (37 lanes x 2 pos) ----
        if (lane < 37) {
            float4 W[5]; float g;
            DSWIN21(W[0], W[1], W[2], W[3], W[4], g, oh_b + (unsigned)lane * 8u);
            h16x2 ev[10], od[10];
            CVT21(ev, od, W, g);
            const unsigned p2 = 2u * (unsigned)lane;
            #pragma unroll
            for (int c = 0; c < 3; ++c) {
                uint4 q0, q1; uint2 q2;
                DSWH10(q0, q1, q2, w_b + (unsigned)c * 48u);
                h16x2 wp[10];
                WPBUILD(wp, q0, q1, q2);
                float e0 = bA[c], e1 = e0;
                #pragma unroll
                for (int i = 0; i < 10; ++i) {
                    e0 = FDOT2(ev[i], wp[i], e0);
                    e1 = FDOT2(od[i], wp[i], e1);
                }
                const unsigned tb = tot_b + (73u * (unsigned)c + p2) * 4u;
                DSW32(tb, fmaxf(e0, 0.f));
                if (p2 + 1 < 73) DSW32(tb + 4u, fmaxf(e1, 0.f));
            }
        }

        // ---- Phase C: conv1 + relu + maxpool2 -> one1[3][128] (64 lanes x 4 pos) ----
        {
            float4 W[6];
            DSWIN24(W[0], W[1], W[2], W[3], W[4], W[5], tot_b + (unsigned)lane * 16u);
            h16x2 ev[11], od[11];
            CVT24(ev, od, W);
            #pragma unroll
            for (int c = 0; c < 3; ++c) {
                uint4 q0, q1; uint2 q2;
                DSWH10(q0, q1, q2, w_b + 144u + (unsigned)c * 48u);
                h16x2 wp[10];
                WPBUILD(wp, q0, q1, q2);
                float a0 = b1[c], a1 = a0, a2 = a0, a3 = a0;
                #pragma unroll
                for (int i = 0; i < 10; ++i) {
                    a0 = FDOT2(ev[i],     wp[i], a0);
                    a1 = FDOT2(od[i],     wp[i], a1);
                    a2 = FDOT2(ev[i + 1], wp[i], a2);
                    a3 = FDOT2(od[i + 1], wp[i], a3);
                }
                float2 st;
                st.x = fmaxf(fmaxf(a0, a1), 0.f);
                st.y = fmaxf(fmaxf(a2, a3), 0.f);
                DSW64(one_b + ((unsigned)c * 128u + 2u * (unsigned)lane) * 4u, st);
            }
        }

        // ---- Phase D: conv2 + relu + maxpool2 -> fa[6] (54 lanes) ----
        if (lane < 54) {
            float acc0[6], acc1[6];
            #pragma unroll
            for (int c2 = 0; c2 < 6; ++c2) { acc0[c2] = b2[c2]; acc1[c2] = acc0[c2]; }
            #pragma unroll
            for (int ch = 0; ch < 3; ++ch) {
                float4 W[5]; float g;
                DSWIN21(W[0], W[1], W[2], W[3], W[4], g,
                        one_b + (unsigned)ch * 512u + (unsigned)lane * 8u);
                h16x2 ev[10], od[10];
                CVT21(ev, od, W, g);
                #pragma unroll
                for (int c2 = 0; c2 < 6; ++c2) {
                    uint4 q0, q1; uint2 q2;
                    DSWH10(q0, q1, q2, wD_b + ((unsigned)c2 * 3u + (unsigned)ch) * 48u);
                    h16x2 wp[10];
                    WPBUILD(wp, q0, q1, q2);
                    #pragma unroll
                    for (int i = 0; i < 10; ++i) {
                        acc0[c2] = FDOT2(ev[i], wp[i], acc0[c2]);
                        acc1[c2] = FDOT2(od[i], wp[i], acc1[c2]);
                    }
                }
            }
            #pragma unroll
            for (int c2 = 0; c2 < 6; ++c2)
                fa[c2] += fmaxf(fmaxf(acc0[c2], acc1[c2]), 0.f);
        }
        cnt += 1.f;
    }

    // ---- final flush ----
    if (lane < 54) {
        float* dst = sums + (size_t)cur * FDIM + lane;
        #pragma unroll
        for (int c2 = 0; c2 < 6; ++c2) atomicAdd(dst + c2 * 54, fa[c2]);
    }
    if (lane == 0) atomicAdd(&counts[cur], cnt);
}

// -------- Kernel 2: per-crystal mean+relu, 324->32 softplus, 32->1 ----------
__global__ __launch_bounds__(64) void head_kernel(
    const float* __restrict__ sums, const float* __restrict__ counts,
    const float* __restrict__ lin_w, const float* __restrict__ lin_b,
    const float* __restrict__ lin1_w, const float* __restrict__ lin1_b,
    float* __restrict__ out)
{
    __shared__ float p[FDIM];
    const int c = blockIdx.x;
    const int lane = threadIdx.x;
    const float inv = 1.0f / fmaxf(counts[c], 1.0f);
    for (int i = lane; i < FDIM; i += 64)
        p[i] = fmaxf(sums[(size_t)c * FDIM + i] * inv, 0.f);
    __syncthreads();

    float r = 0.f;
    if (lane < 32) {
        float acc = lin_b[lane];
        const float* wrow = lin_w + lane * FDIM;
        #pragma unroll 4
        for (int i = 0; i < FDIM; ++i) acc = fmaf(p[i], wrow[i], acc);
        const float sp = (acc > 0.f) ? acc + log1pf(expf(-acc)) : log1pf(expf(acc));
        r = sp * lin1_w[lane];
    }
    #pragma unroll
    for (int off = 16; off; off >>= 1) r += __shfl_down(r, off);
    if (lane == 0) out[c] = r + lin1_b[0];
}

extern "C" void kernel_launch(void* const* d_in, const int* in_sizes, int n_in,
                              void* d_out, int out_size, void* d_ws, size_t ws_size,
                              hipStream_t stream) {
    (void)in_sizes; (void)n_in; (void)out_size; (void)ws_size;
    const float* oh    = (const float*)d_in[0];
    const float* env   = (const float*)d_in[1];
    const int*   idx   = (const int*)  d_in[2];
    // d_in[3] = num_segments (constant 4096)
    const float* wA    = (const float*)d_in[4];
    const float* bA    = (const float*)d_in[5];
    const float* w1    = (const float*)d_in[6];
    const float* b1    = (const float*)d_in[7];
    const float* w2    = (const float*)d_in[8];
    const float* b2    = (const float*)d_in[9];
    const float* lin_w = (const float*)d_in[10];
    const float* lin_b = (const float*)d_in[11];
    const float* lin1_w= (const float*)d_in[12];
    const float* lin1_b= (const float*)d_in[13];

    float* sums   = (float*)d_ws;             // [NC*FDIM]
    float* counts = sums + (size_t)NC * FDIM; // [NC]

    hipMemsetAsync(d_ws, 0, ((size_t)NC * FDIM + NC) * sizeof(float), stream);

    // 8192 blocks x 4 waves x 4 atoms = M0
    atom_kernel<<<M0 / 16, 256, 0, stream>>>(oh, env, idx, wA, bA, w1, b1,
                                             w2, b2, sums, counts);
    head_kernel<<<NC, 64, 0, stream>>>(sums, counts, lin_w, lin_b, lin1_w, lin1_b,
                                       (float*)d_out);
}